// Round 21
// baseline (158.797 us; speedup 1.0000x reference)
//
#include <hip/hip_runtime.h>
#include <stdint.h>

// Problem constants (B=2048, N=16, T=1024)
#define T_STEPS 1024
#define NWORDS  256          // u64 mask words per batch (4 timesteps per word)
#define SCAN_BLOCK 64        // 1 wave: 4 batch-groups x 16 o; 2 chains per lane

typedef float f32x4 __attribute__((ext_vector_type(4)));

// ---------------------------------------------------------------------------
// Kernel 1: spikes -> 16-bit masks, 4 timesteps per u64 (HBM-bound 128 MiB).
// ---------------------------------------------------------------------------
__global__ __launch_bounds__(256) void k_maskify(const float* __restrict__ spike,
                                                 unsigned long long* __restrict__ masks) {
    const int b  = blockIdx.x;
    const int tc = threadIdx.x;
    const float4* sp = reinterpret_cast<const float4*>(spike) + (size_t)b * (16 * NWORDS);
    unsigned int m0 = 0, m1 = 0, m2 = 0, m3 = 0;
#pragma unroll
    for (int i = 0; i < 16; ++i) {
        float4 v = sp[i * NWORDS + tc];
        m0 |= (v.x >= 0.5f) ? (1u << i) : 0u;
        m1 |= (v.y >= 0.5f) ? (1u << i) : 0u;
        m2 |= (v.z >= 0.5f) ? (1u << i) : 0u;
        m3 |= (v.w >= 0.5f) ? (1u << i) : 0u;
    }
    masks[(size_t)b * NWORDS + tc] =
        (unsigned long long)m0 | ((unsigned long long)m1 << 16) |
        ((unsigned long long)m2 << 32) | ((unsigned long long)m3 << 48);
}

// ---------------------------------------------------------------------------
// Kernel 2: CUBA LIF scan — R19's PROVEN LDS body with TWO chains per lane,
// SINGLE-buffered tables (16 live asm doubles = the R14/R19 no-spill zone).
// R19 measured the wall: 77us, VALUBusy 23%, latency-bound serial f64 chain.
// Two independent chains' ZSTEPs are explicitly alternated so the scheduler
// fills each chain's fma/cmp latency with the other chain's work.
// Body(w) ledger (trivial — only my asm touches lgkm in the loop):
//   WAITLG(0) retires prev body's 2 mask prefetches (issued ~300 cyc ago);
//   TISSUE x2 -> 16 ds_reads; DSRM m(w+1) x2 -> 18;
//   WAITLG(2) retires the 16 table reads (masks stay in flight);
//   8 interleaved ZSTEPs; 2 stores (vmcnt, WAITV(16) bound).
// LDS latency (~120cy) exposed once per body, amortized over 2 chain-words.
// Numerics byte-identical to the absmax-0 rounds: table entry =
// (lo-nibble ordered sum)+(hi-nibble ordered sum); z = B0+B1;
// c = fma(c,0.75,z); v = fma(v,0.97,c).
// ---------------------------------------------------------------------------
__global__ __launch_bounds__(SCAN_BLOCK, 1) void k_scan(const float* __restrict__ W,
                                                        const unsigned long long* __restrict__ masks,
                                                        float* __restrict__ out) {
    __shared__ double ztab8[2][256][17];                 // 68 KiB, row 136 B
    __shared__ unsigned long long mlds[8][NWORDS + 1];   // 16.1 KiB

    const int tid = threadIdx.x;
    const int bb  = tid >> 4;          // 0..3
    const int o   = tid & 15;
    const int bx  = blockIdx.x * 8 + bb;
    const int by  = bx + 4;

    // --- Build byte table (hand-verified bijection: (bb,k) -> byte=bb+4k).
    {
        double w[16];
#pragma unroll
        for (int j = 0; j < 16; ++j) w[j] = (double)W[o * 16 + j];
#pragma unroll
        for (int k = 0; k < 128; ++k) {
            const int e    = tid + k * SCAN_BLOCK;
            const int byte = (e >> 4) & 255;
            const int s    = k >> 6;               // COMPILE-TIME constant
            double slo = 0.0, shi = 0.0;
#pragma unroll
            for (int j = 0; j < 4; ++j) slo += (byte & (1 << j))  ? w[8 * s + j]     : 0.0;
#pragma unroll
            for (int j = 0; j < 4; ++j) shi += (byte & (16 << j)) ? w[8 * s + 4 + j] : 0.0;
            ztab8[s][byte][o] = slo + shi;         // = z_{2s} + z_{2s+1}
        }
    }
    // --- Stage masks for this block's 8 batches (coalesced).
    {
        const unsigned long long* src = masks + (size_t)blockIdx.x * 8 * NWORDS;
        for (int e = tid; e < 8 * NWORDS; e += SCAN_BLOCK)
            mlds[e >> 8][e & 255] = src[e];
    }
    __syncthreads();

    const uint32_t tl0  = (uint32_t)(uintptr_t)(&ztab8[0][0][0]) + (uint32_t)(o * 8);
    const uint32_t tl1  = (uint32_t)(uintptr_t)(&ztab8[1][0][0]) + (uint32_t)(o * 8);
    const uint32_t mlbx = (uint32_t)(uintptr_t)(&mlds[bb][0]);
    const uint32_t mlby = (uint32_t)(uintptr_t)(&mlds[bb + 4][0]);

    const uint64_t ob_out = (uint64_t)out;
    const uint32_t vb_ox  = (uint32_t)(bx * (T_STEPS * 4));
    const uint32_t vb_oy  = (uint32_t)(by * (T_STEPS * 4));
    const int grp_sh      = tid & 48;
    const bool writer     = (o == 0);

    double cx = 0.0, vx = 0.0, cy = 0.0, vy = 0.0;
    float px0, px1, px2, px3, py0, py1, py2, py3;

    // ONE full-word table set per chain (single-buffered): 16 live doubles.
    double TAx_0, TAx_1, TAx_2, TAx_3, TAx_4, TAx_5, TAx_6, TAx_7;
    double TAy_0, TAy_1, TAy_2, TAy_3, TAy_4, TAy_5, TAy_6, TAy_7;
    unsigned long long MXa, MYa, MXb, MYb;

#define DSR(DST, ADDR) asm volatile("ds_read_b64 %0, %1" : "=v"(DST) : "v"(ADDR))
#define DSRM(DST, IDX, MLB) do { int _mi = (IDX); if (_mi > 255) _mi = 255;           \
    const uint32_t _a = (MLB) + ((uint32_t)_mi << 3); DSR(DST, _a); } while (0)
#define WAITLG(N) asm volatile("s_waitcnt lgkmcnt(" #N ")" ::: "memory")
#define WAITV(N)  asm volatile("s_waitcnt vmcnt(" #N ")" ::: "memory")
#define SBAR __builtin_amdgcn_sched_barrier(0)

    // 8 ds_read_b64 for one full mask word (R19's exact proven macro).
#define TISSUE(P, MW) do {                                                            \
    const uint32_t _lo = (uint32_t)(MW), _hi = (uint32_t)((MW) >> 32);                \
    uint32_t _a;                                                                      \
    _a = tl0 + (_lo & 255u) * 136u;         DSR(P##_0, _a);                           \
    _a = tl1 + ((_lo >> 8) & 255u) * 136u;  DSR(P##_1, _a);                           \
    _a = tl0 + ((_lo >> 16) & 255u) * 136u; DSR(P##_2, _a);                           \
    _a = tl1 + (_lo >> 24) * 136u;          DSR(P##_3, _a);                           \
    _a = tl0 + (_hi & 255u) * 136u;         DSR(P##_4, _a);                           \
    _a = tl1 + ((_hi >> 8) & 255u) * 136u;  DSR(P##_5, _a);                           \
    _a = tl0 + ((_hi >> 16) & 255u) * 136u; DSR(P##_6, _a);                           \
    _a = tl1 + (_hi >> 24) * 136u;          DSR(P##_7, _a);                           \
} while (0)

    // One recurrence step; numerics identical to the absmax-0 rounds.
#define ZSTEP(CC, VV, ZL, ZH, OWEL) do {                                              \
    const double _z = (ZL) + (ZH);                                                    \
    CC = fma(CC, 0.75, _z);                                                           \
    VV = fma(VV, 0.97, CC);                                                           \
    const bool _s = (VV >= 1.25);                                                     \
    const unsigned long long _bal = __ballot(_s);                                     \
    VV = _s ? 0.0 : VV;                                                               \
    const uint32_t _k = __popc((uint32_t)(_bal >> grp_sh) & 0xFFFFu);                 \
    OWEL = exp2f(fmaf((float)_k, 0.62581400f, 16.0f));                                \
} while (0)

#define STOREW(WD, VB, O0, O1, O2, O3) do {                                           \
    if (writer) {                                                                     \
        f32x4 _ow; _ow.x = O0; _ow.y = O1; _ow.z = O2; _ow.w = O3;                    \
        const uint32_t _vo = (VB) + ((uint32_t)(WD) << 4);                            \
        asm volatile("global_store_dwordx4 %0, %1, %2"                                \
                     :: "v"(_vo), "v"(_ow), "s"(ob_out) : "memory");                  \
    }                                                                                 \
} while (0)

    // Body: uses mask regs MU* (valid), prefetches word WD+1 into ML*.
#define BODY(WD, MUX, MUY, MLX, MLY) do {                                             \
    WAITLG(0); SBAR;               /* retire prev body's 2 mask prefetches */         \
    TISSUE(TAx, MUX);                                                                 \
    TISSUE(TAy, MUY);                                                                 \
    DSRM(MLX, (WD) + 1, mlbx);                                                        \
    DSRM(MLY, (WD) + 1, mlby);                                                        \
    WAITLG(2); SBAR;               /* table word WD ready; masks in flight */         \
    ZSTEP(cx, vx, TAx_0, TAx_1, px0); ZSTEP(cy, vy, TAy_0, TAy_1, py0);               \
    ZSTEP(cx, vx, TAx_2, TAx_3, px1); ZSTEP(cy, vy, TAy_2, TAy_3, py1);               \
    ZSTEP(cx, vx, TAx_4, TAx_5, px2); ZSTEP(cy, vy, TAy_4, TAy_5, py2);               \
    ZSTEP(cx, vx, TAx_6, TAx_7, px3); ZSTEP(cy, vy, TAy_6, TAy_7, py3);               \
    STOREW(WD, vb_ox, px0, px1, px2, px3);                                            \
    STOREW(WD, vb_oy, py0, py1, py2, py3);                                            \
    WAITV(16);                     /* bound store queue (2/body) */                   \
} while (0)

    asm volatile("s_waitcnt vmcnt(0) lgkmcnt(0)" ::: "memory");  // clean ledgers

    // Prologue: masks for word 0.
    DSRM(MXa, 0, mlbx); DSRM(MYa, 0, mlby);
    // (BODY's leading WAITLG(0) will retire these.)

    // Steady: all 256 words, period-2 mask-register swap.
    for (int w = 0; w < 256; w += 2) {
        BODY(w,     MXa, MYa, MXb, MYb);   // uses m(w),   loads m(w+1)->b
        BODY(w + 1, MXb, MYb, MXa, MYa);   // uses m(w+1), loads m(w+2)->a
    }

    asm volatile("s_waitcnt vmcnt(0)" ::: "memory");  // drain stores

#undef DSR
#undef DSRM
#undef WAITLG
#undef WAITV
#undef SBAR
#undef TISSUE
#undef ZSTEP
#undef STOREW
#undef BODY
}

// ---------------------------------------------------------------------------
// Fallback (only if d_ws too small — never observed): R1-style scan.
// ---------------------------------------------------------------------------
__global__ __launch_bounds__(128) void k_scan_fb(const float* __restrict__ W,
                                                 const float* __restrict__ spike,
                                                 float* __restrict__ out) {
    __shared__ double ztab[4][16][16];
    __shared__ unsigned long long mlds[8][NWORDS];
    __shared__ float outtab[17];
    const int tid = threadIdx.x, bb = tid >> 4, o = tid & 15;
    for (int e = tid; e < 4 * 16 * 16; e += 128) {
        const int oo = e & 15, idx = (e >> 4) & 15, seg = e >> 8;
        double s = 0.0;
#pragma unroll
        for (int j = 0; j < 4; ++j)
            if (idx & (1 << j)) s += (double)W[oo * 16 + seg * 4 + j];
        ztab[seg][idx][oo] = s;
    }
    if (tid < 17) {
        const double ln2 = 0.69314718055994530941723212145818;
        const double l2c1 = log(2.0 * cosh(1.0));
        outtab[tid] = (float)exp((16.0 - (double)tid) * ln2 + (double)tid * l2c1);
    }
    {
        const int part = tid & 15;
        const float4* spb = reinterpret_cast<const float4*>(spike) +
                            (size_t)(blockIdx.x * 8 + bb) * (16 * NWORDS);
        for (int w = 0; w < 16; ++w) {
            const int tc = part * 16 + w;
            unsigned int m0 = 0, m1 = 0, m2 = 0, m3 = 0;
#pragma unroll
            for (int i = 0; i < 16; ++i) {
                float4 v = spb[i * NWORDS + tc];
                m0 |= (v.x >= 0.5f) ? (1u << i) : 0u;
                m1 |= (v.y >= 0.5f) ? (1u << i) : 0u;
                m2 |= (v.z >= 0.5f) ? (1u << i) : 0u;
                m3 |= (v.w >= 0.5f) ? (1u << i) : 0u;
            }
            mlds[bb][tc] = (unsigned long long)m0 | ((unsigned long long)m1 << 16) |
                           ((unsigned long long)m2 << 32) | ((unsigned long long)m3 << 48);
        }
    }
    __syncthreads();
    double c = 0.0, v = 0.0;
    const int b = blockIdx.x * 8 + bb;
    float* outp = out + (size_t)b * T_STEPS;
    const int grp_sh = tid & 48;
    const bool writer = (o == 0);
    for (int tg = 0; tg < NWORDS; ++tg) {
        const unsigned long long mw = mlds[bb][tg];
#pragma unroll
        for (int j = 0; j < 4; ++j) {
            const unsigned int m = (unsigned int)(mw >> (16 * j)) & 0xFFFFu;
            const double z = (ztab[0][m & 15][o] + ztab[1][(m >> 4) & 15][o]) +
                             (ztab[2][(m >> 8) & 15][o] + ztab[3][(m >> 12) & 15][o]);
            c = fma(c, 0.75, z);
            v = fma(v, 0.97, c);
            const bool s = (v >= 1.25);
            const unsigned long long bal = __ballot(s);
            v = s ? 0.0 : v;
            if (writer) outp[tg * 4 + j] = outtab[(int)__popcll((bal >> grp_sh) & 0xFFFFull)];
        }
    }
}

extern "C" void kernel_launch(void* const* d_in, const int* in_sizes, int n_in,
                              void* d_out, int out_size, void* d_ws, size_t ws_size,
                              hipStream_t stream) {
    const float* spike = (const float*)d_in[0];
    const float* W     = (const float*)d_in[1];
    float* out         = (float*)d_out;

    const int B = in_sizes[0] / (16 * T_STEPS);  // 2048

    const size_t mask_bytes = (size_t)B * NWORDS * sizeof(unsigned long long);  // 4 MiB

    if (ws_size >= mask_bytes) {
        unsigned long long* masks = (unsigned long long*)d_ws;
        k_maskify<<<B, 256, 0, stream>>>(spike, masks);
        // 2 chains per lane: 256 one-wave blocks (1 wave/CU on all 256 CUs).
        k_scan<<<B / 8, SCAN_BLOCK, 0, stream>>>(W, masks, out);
    } else {
        k_scan_fb<<<B / 8, 128, 0, stream>>>(W, spike, out);
    }
}